// Round 12
// baseline (335.744 us; speedup 1.0000x reference)
//
#include <hip/hip_runtime.h>
#include <hip/hip_bf16.h>
#include <stdint.h>

// OldQuantLinear: y = x @ (scales.T * unpack4(qweight) - zeros.T) + bias
// R12: R8 base (256x256, BK=32, NBUF=4 ring, 32x32x16 MFMA, 1 barrier/tile,
// R8 swizzle, XCD swizzle) + cross-tile fragment pre-read:
//   tail of tile t: pre-read A-ks0 frags of t+1 (afp, 4 b128) -> cluster-0 of
//   t+1 starts with only a 2-read wait (its B frags), and ks1's 6 reads drain
//   under cluster-0's MFMAs. vmcnt shifted one tile earlier (retires t+2 at
//   end of t; prologue vmcnt(4) retires tiles 0 and 1) so buf[(t+1)&3] is
//   published before the tail pre-read.
// R11 lesson: depth-1 + BK=64 regressed; 3-tile lead + BK=32 restored.

#define BM 256
#define BN 256
#define BK 32
#define NBUF 4

using f32x4   = __attribute__((ext_vector_type(4))) float;
using f32x16  = __attribute__((ext_vector_type(16))) float;
using bf16x8  = __attribute__((ext_vector_type(8))) __bf16;

typedef const uint32_t __attribute__((address_space(1)))* gas_ptr;
typedef uint32_t __attribute__((address_space(3)))* las_ptr;

__device__ __forceinline__ void gl16(const __bf16* g, __bf16* l) {
    __builtin_amdgcn_global_load_lds((gas_ptr)g, (las_ptr)l, 16, 0, 0);
}

// ---------------- pre-pass 1: x f32 -> bf16 ----------------
__global__ __launch_bounds__(256) void cvt_x_kernel(
    const float* __restrict__ x, __bf16* __restrict__ xb, size_t n8)
{
    size_t i = (size_t)blockIdx.x * 256 + threadIdx.x;
    if (i >= n8) return;
    const f32x4* p = (const f32x4*)(x + i * 8);
    f32x4 a = p[0], b = p[1];
    bf16x8 v;
    v[0] = (__bf16)a[0]; v[1] = (__bf16)a[1]; v[2] = (__bf16)a[2]; v[3] = (__bf16)a[3];
    v[4] = (__bf16)b[0]; v[5] = (__bf16)b[1]; v[6] = (__bf16)b[2]; v[7] = (__bf16)b[3];
    *(bf16x8*)(xb + i * 8) = v;
}

// ---------------- pre-pass 2: qweight -> Wt [N][K] bf16 ----------------
__global__ __launch_bounds__(256) void dequant_w_kernel(
    const int* __restrict__ qw, const float* __restrict__ scales,
    const float* __restrict__ zeros, __bf16* __restrict__ Wt, int N, int K)
{
    __shared__ __align__(16) __bf16 T[64 * 32 * 8];
    const int tid = threadIdx.x;
    const int nTilesN = N >> 6;
    const int kg0 = (blockIdx.x / nTilesN) << 5;
    const int n0  = (blockIdx.x % nTilesN) << 6;

    #pragma unroll
    for (int it = 0; it < 8; ++it) {
        int idx  = it * 256 + tid;
        int kg_l = idx >> 6, n_l = idx & 63;
        int n = n0 + n_l;
        float s = scales[n], nz = -zeros[n];
        uint32_t w  = (uint32_t)qw[(size_t)(kg0 + kg_l) * N + n];
        uint32_t lo = w & 0x0F0F0F0Fu;
        uint32_t hi = (w >> 4) & 0x0F0F0F0Fu;
        bf16x8 v;
        v[0] = (__bf16)fmaf(s, (float)(lo & 0xFFu),         nz);
        v[1] = (__bf16)fmaf(s, (float)(hi & 0xFFu),         nz);
        v[2] = (__bf16)fmaf(s, (float)((lo >> 8)  & 0xFFu), nz);
        v[3] = (__bf16)fmaf(s, (float)((hi >> 8)  & 0xFFu), nz);
        v[4] = (__bf16)fmaf(s, (float)((lo >> 16) & 0xFFu), nz);
        v[5] = (__bf16)fmaf(s, (float)((hi >> 16) & 0xFFu), nz);
        v[6] = (__bf16)fmaf(s, (float)(lo >> 24),           nz);
        v[7] = (__bf16)fmaf(s, (float)(hi >> 24),           nz);
        int slot = kg_l ^ (n_l & 7);
        *(bf16x8*)&T[(size_t)(n_l * 32 + slot) * 8] = v;
    }
    __syncthreads();
    #pragma unroll
    for (int it = 0; it < 8; ++it) {
        int idx  = it * 256 + tid;
        int n_l  = idx >> 5, kg_l = idx & 31;
        bf16x8 v = *(const bf16x8*)&T[(size_t)(n_l * 32 + (kg_l ^ (n_l & 7))) * 8];
        *(bf16x8*)&Wt[(size_t)(n0 + n_l) * K + (size_t)(kg0 + kg_l) * 8] = v;
    }
}

// ------- main GEMM: 256x256, 8 waves, 4-ring, 32x32x16, frag pre-read ------
__global__ __launch_bounds__(512) void qgemm8_kernel(
    const __bf16* __restrict__ A, const __bf16* __restrict__ Bt,
    const float* __restrict__ bias, float* __restrict__ out,
    int M, int N, int K)
{
    __shared__ __align__(16) __bf16 Alds[NBUF * BM * BK];  // 64 KiB
    __shared__ __align__(16) __bf16 Blds[NBUF * BN * BK];  // 64 KiB

    const int tid = threadIdx.x;
    const int l   = tid & 63;
    const int w   = tid >> 6;
    const int wm  = w >> 2;        // 0..1 (M half, 128 rows)
    const int wn  = w & 3;         // 0..3 (N quarter, 64 cols)
    const int l31 = l & 31;
    const int lk  = l >> 5;        // 0..1 (k-half within fragment)

    // T1: bijective XCD swizzle (nwg % 8 == 0 for our shapes)
    int bid = (int)blockIdx.x;
    const int nwg = (int)gridDim.x;
    if ((nwg & 7) == 0) bid = (bid & 7) * (nwg >> 3) + (bid >> 3);

    const int nTilesN = N / BN;
    const int brow = (bid / nTilesN) * BM;
    const int bcol = (bid % nTilesN) * BN;

    // staging (R8, proven): gi = w*128 + j*64 + l; row = w*32 + j*16 + (l>>2);
    // slot_pos = l&3; content k-granule kb = (l&3) ^ ((l>>3)&3)
    const int skb  = (l & 3) ^ ((l >> 3) & 3);
    const int srow = w * 32 + (l >> 2);
    const __bf16* aS0 = A  + (size_t)(brow + srow) * K + skb * 8;
    const __bf16* aS1 = aS0 + (size_t)16 * K;
    const __bf16* bS0 = Bt + (size_t)(bcol + srow) * K + skb * 8;
    const __bf16* bS1 = bS0 + (size_t)16 * K;
    __bf16* aD0 = &Alds[(w * 128) * 8];       // wave-uniform; HW adds lane*16B
    __bf16* aD1 = &Alds[(w * 128 + 64) * 8];
    __bf16* bD0 = &Blds[(w * 128) * 8];
    __bf16* bD1 = &Blds[(w * 128 + 64) * 8];

    #define STAGE_A(tt) { const size_t ko = (size_t)(tt) * BK;            \
        const int sb = ((tt) & 3) * (BM * BK);                            \
        gl16(aS0 + ko, aD0 + sb); gl16(aS1 + ko, aD1 + sb); }
    #define STAGE_B(tt) { const size_t ko = (size_t)(tt) * BK;            \
        const int sb = ((tt) & 3) * (BN * BK);                            \
        gl16(bS0 + ko, bD0 + sb); gl16(bS1 + ko, bD1 + sb); }

    f32x16 acc[4][2];
    #pragma unroll
    for (int i = 0; i < 4; ++i)
        #pragma unroll
        for (int j = 0; j < 2; ++j)
            acc[i][j] = (f32x16)(0.f);

    const int NT = K / BK;

    // fragment reads (R8): row = base + l31, kg = ks*2 + lk,
    // slot = kg ^ rsw, rsw = (l31>>1)&3 (mf/nf-invariant; bases mult of 32)
    const int rsw  = (l31 >> 1) & 3;
    const int rsp0 = lk ^ rsw;
    const int rsp1 = (2 + lk) ^ rsw;
    const int arow   = wm * 128 + l31;        // + mf*32
    const int brow_f = wn * 64 + l31;         // + nf*32

    // prologue: stage tiles 0,1,2; retire tiles 0 AND 1 (12 -> 4 in flight);
    // publish; pre-read A-ks0 frags of tile 0.
    STAGE_A(0); STAGE_B(0);
    STAGE_A(1); STAGE_B(1);
    STAGE_A(2); STAGE_B(2);
    asm volatile("s_waitcnt vmcnt(4)" ::: "memory");
    __builtin_amdgcn_s_barrier();

    bf16x8 afp[4];
    #pragma unroll
    for (int mf = 0; mf < 4; ++mf)
        afp[mf] = *(const bf16x8*)&Alds[(arow + mf * 32) * BK + rsp0 * 8];

    for (int t = 0; t < NT; ++t) {
        const int bo   = (t & 3) * (BM * BK);
        const int bo_n = ((t + 1) & 3) * (BM * BK);
        const bool pre = (t + 3 < NT);
        bf16x8 bfr[2], af2[4], bfr2[2];

        __builtin_amdgcn_sched_barrier(0);   // nothing crosses the barrier from below

        // ks0 B reads (cluster-0 only waits on these 2; afp drained already)
        #pragma unroll
        for (int nf = 0; nf < 2; ++nf)
            bfr[nf] = *(const bf16x8*)&Blds[bo + (brow_f + nf * 32) * BK + rsp0 * 8];
        // ks1 reads — drain under cluster-0's MFMAs
        #pragma unroll
        for (int mf = 0; mf < 4; ++mf)
            af2[mf] = *(const bf16x8*)&Alds[bo + (arow + mf * 32) * BK + rsp1 * 8];
        #pragma unroll
        for (int nf = 0; nf < 2; ++nf)
            bfr2[nf] = *(const bf16x8*)&Blds[bo + (brow_f + nf * 32) * BK + rsp1 * 8];
        if (pre) STAGE_A(t + 3);

        // ---- cluster 0: ks0, A from afp (pre-read at tail of t-1) ----
        __builtin_amdgcn_s_setprio(1);
        #pragma unroll
        for (int mf = 0; mf < 4; ++mf)
            #pragma unroll
            for (int nf = 0; nf < 2; ++nf)
                acc[mf][nf] = __builtin_amdgcn_mfma_f32_32x32x16_bf16(
                    afp[mf], bfr[nf], acc[mf][nf], 0, 0, 0);
        __builtin_amdgcn_s_setprio(0);

        if (pre) STAGE_B(t + 3);

        // ---- cluster 1: ks1 ----
        __builtin_amdgcn_s_setprio(1);
        #pragma unroll
        for (int mf = 0; mf < 4; ++mf)
            #pragma unroll
            for (int nf = 0; nf < 2; ++nf)
                acc[mf][nf] = __builtin_amdgcn_mfma_f32_32x32x16_bf16(
                    af2[mf], bfr2[nf], acc[mf][nf], 0, 0, 0);
        __builtin_amdgcn_s_setprio(0);

        // tail: pre-read A-ks0 of t+1 (buf published at end of t-1)
        if (t + 1 < NT) {
            #pragma unroll
            for (int mf = 0; mf < 4; ++mf)
                afp[mf] = *(const bf16x8*)&Alds[bo_n + (arow + mf * 32) * BK + rsp0 * 8];
        }

        // counted vmcnt: retire tile t+2's 4 loads (one tile earlier than R8)
        if (pre) { asm volatile("s_waitcnt vmcnt(4)" ::: "memory"); }
        else     { asm volatile("s_waitcnt vmcnt(0)" ::: "memory"); }
        __builtin_amdgcn_sched_barrier(0);   // nothing crosses from above
        __builtin_amdgcn_s_barrier();        // ONE barrier per K-tile
    }

    // ---- epilogue: 32x32 C/D layout: col = l31, row = (r&3)+8*(r>>2)+4*lk ----
    #pragma unroll
    for (int nf = 0; nf < 2; ++nf) {
        int col = bcol + wn * 64 + nf * 32 + l31;
        float bv = bias[col];
        #pragma unroll
        for (int mf = 0; mf < 4; ++mf) {
            int row0 = brow + wm * 128 + mf * 32 + 4 * lk;
            #pragma unroll
            for (int r = 0; r < 16; ++r) {
                int row = row0 + (r & 3) + 8 * (r >> 2);
                out[(size_t)row * N + col] = acc[mf][nf][r] + bv;
            }
        }
    }
    #undef STAGE_A
    #undef STAGE_B
}

// ---------------- fallback: fused kernel (R2) ----------------
#define FT_M 128
#define FT_N 128
#define FT_K 64
__global__ __launch_bounds__(256) void qgemm_fused_kernel(
    const float* __restrict__ x, const int* __restrict__ qw,
    const float* __restrict__ scales, const float* __restrict__ zeros,
    const float* __restrict__ bias, float* __restrict__ out,
    int M, int N, int K)
{
    __shared__ __align__(16) __bf16 Alds[FT_M * FT_K];
    __shared__ __align__(16) __bf16 Blds[FT_N * FT_K];

    const int tid  = threadIdx.x;
    const int lane = tid & 63;
    const int wave = tid >> 6;
    const int wm = wave >> 1, wn = wave & 1;
    const int lrow = lane & 15, lkb = lane >> 4;

    const int nTilesN = N / FT_N;
    const int brow = (blockIdx.x / nTilesN) * FT_M;
    const int bcol = (blockIdx.x % nTilesN) * FT_N;

    const int bc  = tid & 127;
    const int qr0 = tid >> 7;
    const float s  = scales[bcol + bc];
    const float nz = -zeros[bcol + bc];

    f32x4 acc[4][4];
    #pragma unroll
    for (int i = 0; i < 4; ++i)
        #pragma unroll
        for (int j = 0; j < 4; ++j)
            acc[i][j] = (f32x4){0.f, 0.f, 0.f, 0.f};

    for (int kt = 0; kt < K; kt += FT_K) {
        #pragma unroll
        for (int i = 0; i < 4; ++i) {
            int g  = tid + i * 256;
            int r  = g >> 3;
            int kbg = g & 7;
            const float* p = x + (size_t)(brow + r) * K + kt + kbg * 8;
            f32x4 f0 = *(const f32x4*)p;
            f32x4 f1 = *(const f32x4*)(p + 4);
            bf16x8 v;
            v[0] = (__bf16)f0[0]; v[1] = (__bf16)f0[1];
            v[2] = (__bf16)f0[2]; v[3] = (__bf16)f0[3];
            v[4] = (__bf16)f1[0]; v[5] = (__bf16)f1[1];
            v[6] = (__bf16)f1[2]; v[7] = (__bf16)f1[3];
            int slot = kbg ^ (r & 7);
            *(bf16x8*)&Alds[r * FT_K + slot * 8] = v;
        }
        #pragma unroll
        for (int i = 0; i < 4; ++i) {
            int qr = qr0 + i * 2;
            uint32_t wv = (uint32_t)qw[(size_t)(kt / 8 + qr) * N + bcol + bc];
            uint32_t lo = wv & 0x0F0F0F0Fu;
            uint32_t hi = (wv >> 4) & 0x0F0F0F0Fu;
            bf16x8 v;
            v[0] = (__bf16)fmaf(s, (float)(lo & 0xFFu),         nz);
            v[1] = (__bf16)fmaf(s, (float)(hi & 0xFFu),         nz);
            v[2] = (__bf16)fmaf(s, (float)((lo >> 8)  & 0xFFu), nz);
            v[3] = (__bf16)fmaf(s, (float)((hi >> 8)  & 0xFFu), nz);
            v[4] = (__bf16)fmaf(s, (float)((lo >> 16) & 0xFFu), nz);
            v[5] = (__bf16)fmaf(s, (float)((hi >> 16) & 0xFFu), nz);
            v[6] = (__bf16)fmaf(s, (float)(lo >> 24),           nz);
            v[7] = (__bf16)fmaf(s, (float)(hi >> 24),           nz);
            int slot = qr ^ (bc & 7);
            *(bf16x8*)&Blds[bc * FT_K + slot * 8] = v;
        }
        __syncthreads();

        #pragma unroll
        for (int ks = 0; ks < 2; ++ks) {
            const int slot = (ks * 4 + lkb) ^ (lrow & 7);
            const int abase = (wm * 64 + lrow) * FT_K + slot * 8;
            const int bbase = (wn * 64 + lrow) * FT_K + slot * 8;
            bf16x8 af[4], bfr[4];
            #pragma unroll
            for (int mf = 0; mf < 4; ++mf)
                af[mf] = *(const bf16x8*)&Alds[abase + mf * 16 * FT_K];
            #pragma unroll
            for (int nf = 0; nf < 4; ++nf)
                bfr[nf] = *(const bf16x8*)&Blds[bbase + nf * 16 * FT_K];
            #pragma unroll
            for (int mf = 0; mf < 4; ++mf)
                #pragma unroll
                for (int nf = 0; nf < 4; ++nf)
                    acc[mf][nf] = __builtin_amdgcn_mfma_f32_16x16x32_bf16(
                        af[mf], bfr[nf], acc[mf][nf], 0, 0, 0);
        }
        __syncthreads();
    }

    #pragma unroll
    for (int nf = 0; nf < 4; ++nf) {
        int col = bcol + wn * 64 + nf * 16 + lrow;
        float bv = bias[col];
        #pragma unroll
        for (int mf = 0; mf < 4; ++mf) {
            int row = brow + wm * 64 + mf * 16 + lkb * 4;
            #pragma unroll
            for (int i = 0; i < 4; ++i)
                out[(size_t)(row + i) * N + col] = acc[mf][nf][i] + bv;
        }
    }
}

extern "C" void kernel_launch(void* const* d_in, const int* in_sizes, int n_in,
                              void* d_out, int out_size, void* d_ws, size_t ws_size,
                              hipStream_t stream) {
    const float* x      = (const float*)d_in[0];
    const int*   qw     = (const int*)d_in[1];
    const float* scales = (const float*)d_in[2];
    const float* zeros  = (const float*)d_in[3];
    const float* bias   = (const float*)d_in[4];
    float* out = (float*)d_out;

    const int N = in_sizes[4];                              // OUT
    const int K = (int)(((long long)in_sizes[1] * 8) / N);  // IN
    const int M = in_sizes[0] / K;

    const size_t xb_elems = (size_t)M * K;
    const size_t wt_elems = (size_t)N * K;
    const size_t need = (xb_elems + wt_elems) * sizeof(__bf16);

    const bool shapes_ok = (M % BM == 0) && (N % BN == 0) && (K % 256 == 0) &&
                           (K / BK >= 4);

    if (ws_size >= need && shapes_ok) {
        __bf16* xb = (__bf16*)d_ws;
        __bf16* Wt = xb + xb_elems;

        size_t n8 = xb_elems / 8;
        cvt_x_kernel<<<dim3((unsigned)((n8 + 255) / 256)), 256, 0, stream>>>(x, xb, n8);

        dim3 dq_grid((unsigned)(((K / 8) / 32) * (N / 64)));
        dequant_w_kernel<<<dq_grid, 256, 0, stream>>>(qw, scales, zeros, Wt, N, K);

        dim3 grid((M / BM) * (N / BN));
        qgemm8_kernel<<<grid, 512, 0, stream>>>(xb, Wt, bias, out, M, N, K);
    } else {
        dim3 grid((M / FT_M) * (N / FT_N));
        qgemm_fused_kernel<<<grid, 256, 0, stream>>>(x, qw, scales, zeros, bias, out, M, N, K);
    }
}

// Round 13
// 309.383 us; speedup vs baseline: 1.0852x; 1.0852x over previous
//
#include <hip/hip_runtime.h>
#include <hip/hip_bf16.h>
#include <stdint.h>

// OldQuantLinear: y = x @ (scales.T * unpack4(qweight) - zeros.T) + bias
// R13: R8 base (256x256, BK=32, NBUF=4 ring, 32x32x16 MFMA, R8 swizzle,
// XCD swizzle, setprio) with barrier every TWO K-tiles:
//   pair (t,t+1), t even: {rd ks0(t); STAGE_A(t+2); mfma; rd ks1(t);
//   STAGE_B(t+2); mfma; rd ks0(t+1); STAGE_A(t+3); mfma; rd ks1(t+1);
//   STAGE_B(t+3); mfma; vmcnt(0); barrier}
// No barrier between t and t+1 -> t+1's ds_reads (retired at previous pair's
// vmcnt(0)) overlap t's MFMAs; LDS port busy through MFMA phases.
// Hazards: pair reads bufs {t,t+1}&3, stages {t+2,t+3}&3 (all distinct);
// stage targets' prior readers finished before pair-entry barrier.
// vmcnt(0) drain is >=1.5 tiles after newest issue (R11's mistake was a
// 0.4-tile drain distance). R12's cross-tile reg pre-read reverted.

#define BM 256
#define BN 256
#define BK 32
#define NBUF 4

using f32x4   = __attribute__((ext_vector_type(4))) float;
using f32x16  = __attribute__((ext_vector_type(16))) float;
using bf16x8  = __attribute__((ext_vector_type(8))) __bf16;

typedef const uint32_t __attribute__((address_space(1)))* gas_ptr;
typedef uint32_t __attribute__((address_space(3)))* las_ptr;

__device__ __forceinline__ void gl16(const __bf16* g, __bf16* l) {
    __builtin_amdgcn_global_load_lds((gas_ptr)g, (las_ptr)l, 16, 0, 0);
}

// ---------------- pre-pass 1: x f32 -> bf16 ----------------
__global__ __launch_bounds__(256) void cvt_x_kernel(
    const float* __restrict__ x, __bf16* __restrict__ xb, size_t n8)
{
    size_t i = (size_t)blockIdx.x * 256 + threadIdx.x;
    if (i >= n8) return;
    const f32x4* p = (const f32x4*)(x + i * 8);
    f32x4 a = p[0], b = p[1];
    bf16x8 v;
    v[0] = (__bf16)a[0]; v[1] = (__bf16)a[1]; v[2] = (__bf16)a[2]; v[3] = (__bf16)a[3];
    v[4] = (__bf16)b[0]; v[5] = (__bf16)b[1]; v[6] = (__bf16)b[2]; v[7] = (__bf16)b[3];
    *(bf16x8*)(xb + i * 8) = v;
}

// ---------------- pre-pass 2: qweight -> Wt [N][K] bf16 ----------------
__global__ __launch_bounds__(256) void dequant_w_kernel(
    const int* __restrict__ qw, const float* __restrict__ scales,
    const float* __restrict__ zeros, __bf16* __restrict__ Wt, int N, int K)
{
    __shared__ __align__(16) __bf16 T[64 * 32 * 8];
    const int tid = threadIdx.x;
    const int nTilesN = N >> 6;
    const int kg0 = (blockIdx.x / nTilesN) << 5;
    const int n0  = (blockIdx.x % nTilesN) << 6;

    #pragma unroll
    for (int it = 0; it < 8; ++it) {
        int idx  = it * 256 + tid;
        int kg_l = idx >> 6, n_l = idx & 63;
        int n = n0 + n_l;
        float s = scales[n], nz = -zeros[n];
        uint32_t w  = (uint32_t)qw[(size_t)(kg0 + kg_l) * N + n];
        uint32_t lo = w & 0x0F0F0F0Fu;
        uint32_t hi = (w >> 4) & 0x0F0F0F0Fu;
        bf16x8 v;
        v[0] = (__bf16)fmaf(s, (float)(lo & 0xFFu),         nz);
        v[1] = (__bf16)fmaf(s, (float)(hi & 0xFFu),         nz);
        v[2] = (__bf16)fmaf(s, (float)((lo >> 8)  & 0xFFu), nz);
        v[3] = (__bf16)fmaf(s, (float)((hi >> 8)  & 0xFFu), nz);
        v[4] = (__bf16)fmaf(s, (float)((lo >> 16) & 0xFFu), nz);
        v[5] = (__bf16)fmaf(s, (float)((hi >> 16) & 0xFFu), nz);
        v[6] = (__bf16)fmaf(s, (float)(lo >> 24),           nz);
        v[7] = (__bf16)fmaf(s, (float)(hi >> 24),           nz);
        int slot = kg_l ^ (n_l & 7);
        *(bf16x8*)&T[(size_t)(n_l * 32 + slot) * 8] = v;
    }
    __syncthreads();
    #pragma unroll
    for (int it = 0; it < 8; ++it) {
        int idx  = it * 256 + tid;
        int n_l  = idx >> 5, kg_l = idx & 31;
        bf16x8 v = *(const bf16x8*)&T[(size_t)(n_l * 32 + (kg_l ^ (n_l & 7))) * 8];
        *(bf16x8*)&Wt[(size_t)(n0 + n_l) * K + (size_t)(kg0 + kg_l) * 8] = v;
    }
}

// ------- main GEMM: 256x256, 8 waves, 4-ring, 32x32x16, barrier/2-tiles ----
__global__ __launch_bounds__(512) void qgemm8_kernel(
    const __bf16* __restrict__ A, const __bf16* __restrict__ Bt,
    const float* __restrict__ bias, float* __restrict__ out,
    int M, int N, int K)
{
    __shared__ __align__(16) __bf16 Alds[NBUF * BM * BK];  // 64 KiB
    __shared__ __align__(16) __bf16 Blds[NBUF * BN * BK];  // 64 KiB

    const int tid = threadIdx.x;
    const int l   = tid & 63;
    const int w   = tid >> 6;
    const int wm  = w >> 2;        // 0..1 (M half, 128 rows)
    const int wn  = w & 3;         // 0..3 (N quarter, 64 cols)
    const int l31 = l & 31;
    const int lk  = l >> 5;        // 0..1 (k-half within fragment)

    // T1: bijective XCD swizzle (nwg % 8 == 0 for our shapes)
    int bid = (int)blockIdx.x;
    const int nwg = (int)gridDim.x;
    if ((nwg & 7) == 0) bid = (bid & 7) * (nwg >> 3) + (bid >> 3);

    const int nTilesN = N / BN;
    const int brow = (bid / nTilesN) * BM;
    const int bcol = (bid % nTilesN) * BN;

    // staging (R8, proven): gi = w*128 + j*64 + l; row = w*32 + j*16 + (l>>2);
    // slot_pos = l&3; content k-granule kb = (l&3) ^ ((l>>3)&3)
    const int skb  = (l & 3) ^ ((l >> 3) & 3);
    const int srow = w * 32 + (l >> 2);
    const __bf16* aS0 = A  + (size_t)(brow + srow) * K + skb * 8;
    const __bf16* aS1 = aS0 + (size_t)16 * K;
    const __bf16* bS0 = Bt + (size_t)(bcol + srow) * K + skb * 8;
    const __bf16* bS1 = bS0 + (size_t)16 * K;
    __bf16* aD0 = &Alds[(w * 128) * 8];       // wave-uniform; HW adds lane*16B
    __bf16* aD1 = &Alds[(w * 128 + 64) * 8];
    __bf16* bD0 = &Blds[(w * 128) * 8];
    __bf16* bD1 = &Blds[(w * 128 + 64) * 8];

    #define STAGE_A(tt) { const size_t ko = (size_t)(tt) * BK;            \
        const int sb = ((tt) & 3) * (BM * BK);                            \
        gl16(aS0 + ko, aD0 + sb); gl16(aS1 + ko, aD1 + sb); }
    #define STAGE_B(tt) { const size_t ko = (size_t)(tt) * BK;            \
        const int sb = ((tt) & 3) * (BN * BK);                            \
        gl16(bS0 + ko, bD0 + sb); gl16(bS1 + ko, bD1 + sb); }

    f32x16 acc[4][2];
    #pragma unroll
    for (int i = 0; i < 4; ++i)
        #pragma unroll
        for (int j = 0; j < 2; ++j)
            acc[i][j] = (f32x16)(0.f);

    const int NT = K / BK;

    // fragment reads (R8): row = base + l31, kg = ks*2 + lk,
    // slot = kg ^ rsw, rsw = (l31>>1)&3 (mf/nf-invariant; bases mult of 32)
    const int rsw  = (l31 >> 1) & 3;
    const int rsp0 = lk ^ rsw;
    const int rsp1 = (2 + lk) ^ rsw;
    const int arow   = wm * 128 + l31;        // + mf*32
    const int brow_f = wn * 64 + l31;         // + nf*32

    // one K-tile of compute from buffer offset bo, with the two stage slots
    #define TILE_BODY(bo, stA, stB, doA, doB) {                               \
        bf16x8 af[4], bfr[2];                                                 \
        _Pragma("unroll")                                                     \
        for (int mf = 0; mf < 4; ++mf)                                        \
            af[mf] = *(const bf16x8*)&Alds[(bo) + (arow + mf * 32) * BK + rsp0 * 8]; \
        _Pragma("unroll")                                                     \
        for (int nf = 0; nf < 2; ++nf)                                        \
            bfr[nf] = *(const bf16x8*)&Blds[(bo) + (brow_f + nf * 32) * BK + rsp0 * 8]; \
        if (doA) STAGE_A(stA);                                                \
        __builtin_amdgcn_s_setprio(1);                                        \
        _Pragma("unroll")                                                     \
        for (int mf = 0; mf < 4; ++mf)                                        \
            _Pragma("unroll")                                                 \
            for (int nf = 0; nf < 2; ++nf)                                    \
                acc[mf][nf] = __builtin_amdgcn_mfma_f32_32x32x16_bf16(        \
                    af[mf], bfr[nf], acc[mf][nf], 0, 0, 0);                   \
        __builtin_amdgcn_s_setprio(0);                                        \
        _Pragma("unroll")                                                     \
        for (int mf = 0; mf < 4; ++mf)                                        \
            af[mf] = *(const bf16x8*)&Alds[(bo) + (arow + mf * 32) * BK + rsp1 * 8]; \
        _Pragma("unroll")                                                     \
        for (int nf = 0; nf < 2; ++nf)                                        \
            bfr[nf] = *(const bf16x8*)&Blds[(bo) + (brow_f + nf * 32) * BK + rsp1 * 8]; \
        if (doB) STAGE_B(stB);                                                \
        __builtin_amdgcn_s_setprio(1);                                        \
        _Pragma("unroll")                                                     \
        for (int mf = 0; mf < 4; ++mf)                                        \
            _Pragma("unroll")                                                 \
            for (int nf = 0; nf < 2; ++nf)                                    \
                acc[mf][nf] = __builtin_amdgcn_mfma_f32_32x32x16_bf16(        \
                    af[mf], bfr[nf], acc[mf][nf], 0, 0, 0);                   \
        __builtin_amdgcn_s_setprio(0);                                        \
    }

    // prologue: stage tiles 0 and 1; drain; join
    STAGE_A(0); STAGE_B(0);
    STAGE_A(1); STAGE_B(1);
    asm volatile("s_waitcnt vmcnt(0)" ::: "memory");
    __builtin_amdgcn_s_barrier();

    for (int t = 0; t < NT; t += 2) {
        const int bo0 = (t & 3) * (BM * BK);
        const int bo1 = ((t + 1) & 3) * (BM * BK);
        const bool p2 = (t + 2 < NT);
        const bool p3 = (t + 3 < NT);

        __builtin_amdgcn_sched_barrier(0);   // pin loop top

        TILE_BODY(bo0, t + 2, t + 2, p2, p2);   // tile t,   stages tile t+2
        TILE_BODY(bo1, t + 3, t + 3, p3, p3);   // tile t+1, stages tile t+3

        // drain the pair's 8 staged loads (issued >=1.5 tiles ago) and sync
        asm volatile("s_waitcnt vmcnt(0)" ::: "memory");
        __builtin_amdgcn_sched_barrier(0);
        __builtin_amdgcn_s_barrier();        // ONE barrier per 2 K-tiles
    }

    // ---- epilogue: 32x32 C/D layout: col = l31, row = (r&3)+8*(r>>2)+4*lk ----
    #pragma unroll
    for (int nf = 0; nf < 2; ++nf) {
        int col = bcol + wn * 64 + nf * 32 + l31;
        float bv = bias[col];
        #pragma unroll
        for (int mf = 0; mf < 4; ++mf) {
            int row0 = brow + wm * 128 + mf * 32 + 4 * lk;
            #pragma unroll
            for (int r = 0; r < 16; ++r) {
                int row = row0 + (r & 3) + 8 * (r >> 2);
                out[(size_t)row * N + col] = acc[mf][nf][r] + bv;
            }
        }
    }
    #undef TILE_BODY
    #undef STAGE_A
    #undef STAGE_B
}

// ---------------- fallback: fused kernel (R2) ----------------
#define FT_M 128
#define FT_N 128
#define FT_K 64
__global__ __launch_bounds__(256) void qgemm_fused_kernel(
    const float* __restrict__ x, const int* __restrict__ qw,
    const float* __restrict__ scales, const float* __restrict__ zeros,
    const float* __restrict__ bias, float* __restrict__ out,
    int M, int N, int K)
{
    __shared__ __align__(16) __bf16 Alds[FT_M * FT_K];
    __shared__ __align__(16) __bf16 Blds[FT_N * FT_K];

    const int tid  = threadIdx.x;
    const int lane = tid & 63;
    const int wave = tid >> 6;
    const int wm = wave >> 1, wn = wave & 1;
    const int lrow = lane & 15, lkb = lane >> 4;

    const int nTilesN = N / FT_N;
    const int brow = (blockIdx.x / nTilesN) * FT_M;
    const int bcol = (blockIdx.x % nTilesN) * FT_N;

    const int bc  = tid & 127;
    const int qr0 = tid >> 7;
    const float s  = scales[bcol + bc];
    const float nz = -zeros[bcol + bc];

    f32x4 acc[4][4];
    #pragma unroll
    for (int i = 0; i < 4; ++i)
        #pragma unroll
        for (int j = 0; j < 4; ++j)
            acc[i][j] = (f32x4){0.f, 0.f, 0.f, 0.f};

    for (int kt = 0; kt < K; kt += FT_K) {
        #pragma unroll
        for (int i = 0; i < 4; ++i) {
            int g  = tid + i * 256;
            int r  = g >> 3;
            int kbg = g & 7;
            const float* p = x + (size_t)(brow + r) * K + kt + kbg * 8;
            f32x4 f0 = *(const f32x4*)p;
            f32x4 f1 = *(const f32x4*)(p + 4);
            bf16x8 v;
            v[0] = (__bf16)f0[0]; v[1] = (__bf16)f0[1];
            v[2] = (__bf16)f0[2]; v[3] = (__bf16)f0[3];
            v[4] = (__bf16)f1[0]; v[5] = (__bf16)f1[1];
            v[6] = (__bf16)f1[2]; v[7] = (__bf16)f1[3];
            int slot = kbg ^ (r & 7);
            *(bf16x8*)&Alds[r * FT_K + slot * 8] = v;
        }
        #pragma unroll
        for (int i = 0; i < 4; ++i) {
            int qr = qr0 + i * 2;
            uint32_t wv = (uint32_t)qw[(size_t)(kt / 8 + qr) * N + bcol + bc];
            uint32_t lo = wv & 0x0F0F0F0Fu;
            uint32_t hi = (wv >> 4) & 0x0F0F0F0Fu;
            bf16x8 v;
            v[0] = (__bf16)fmaf(s, (float)(lo & 0xFFu),         nz);
            v[1] = (__bf16)fmaf(s, (float)(hi & 0xFFu),         nz);
            v[2] = (__bf16)fmaf(s, (float)((lo >> 8)  & 0xFFu), nz);
            v[3] = (__bf16)fmaf(s, (float)((hi >> 8)  & 0xFFu), nz);
            v[4] = (__bf16)fmaf(s, (float)((lo >> 16) & 0xFFu), nz);
            v[5] = (__bf16)fmaf(s, (float)((hi >> 16) & 0xFFu), nz);
            v[6] = (__bf16)fmaf(s, (float)(lo >> 24),           nz);
            v[7] = (__bf16)fmaf(s, (float)(hi >> 24),           nz);
            int slot = qr ^ (bc & 7);
            *(bf16x8*)&Blds[bc * FT_K + slot * 8] = v;
        }
        __syncthreads();

        #pragma unroll
        for (int ks = 0; ks < 2; ++ks) {
            const int slot = (ks * 4 + lkb) ^ (lrow & 7);
            const int abase = (wm * 64 + lrow) * FT_K + slot * 8;
            const int bbase = (wn * 64 + lrow) * FT_K + slot * 8;
            bf16x8 af[4], bfr[4];
            #pragma unroll
            for (int mf = 0; mf < 4; ++mf)
                af[mf] = *(const bf16x8*)&Alds[abase + mf * 16 * FT_K];
            #pragma unroll
            for (int nf = 0; nf < 4; ++nf)
                bfr[nf] = *(const bf16x8*)&Blds[bbase + nf * 16 * FT_K];
            #pragma unroll
            for (int mf = 0; mf < 4; ++mf)
                #pragma unroll
                for (int nf = 0; nf < 4; ++nf)
                    acc[mf][nf] = __builtin_amdgcn_mfma_f32_16x16x32_bf16(
                        af[mf], bfr[nf], acc[mf][nf], 0, 0, 0);
        }
        __syncthreads();
    }

    #pragma unroll
    for (int nf = 0; nf < 4; ++nf) {
        int col = bcol + wn * 64 + nf * 16 + lrow;
        float bv = bias[col];
        #pragma unroll
        for (int mf = 0; mf < 4; ++mf) {
            int row = brow + wm * 64 + mf * 16 + lkb * 4;
            #pragma unroll
            for (int i = 0; i < 4; ++i)
                out[(size_t)(row + i) * N + col] = acc[mf][nf][i] + bv;
        }
    }
}

extern "C" void kernel_launch(void* const* d_in, const int* in_sizes, int n_in,
                              void* d_out, int out_size, void* d_ws, size_t ws_size,
                              hipStream_t stream) {
    const float* x      = (const float*)d_in[0];
    const int*   qw     = (const int*)d_in[1];
    const float* scales = (const float*)d_in[2];
    const float* zeros  = (const float*)d_in[3];
    const float* bias   = (const float*)d_in[4];
    float* out = (float*)d_out;

    const int N = in_sizes[4];                              // OUT
    const int K = (int)(((long long)in_sizes[1] * 8) / N);  // IN
    const int M = in_sizes[0] / K;

    const size_t xb_elems = (size_t)M * K;
    const size_t wt_elems = (size_t)N * K;
    const size_t need = (xb_elems + wt_elems) * sizeof(__bf16);

    const bool shapes_ok = (M % BM == 0) && (N % BN == 0) && (K % 256 == 0) &&
                           ((K / BK) % 2 == 0) && (K / BK >= 4);

    if (ws_size >= need && shapes_ok) {
        __bf16* xb = (__bf16*)d_ws;
        __bf16* Wt = xb + xb_elems;

        size_t n8 = xb_elems / 8;
        cvt_x_kernel<<<dim3((unsigned)((n8 + 255) / 256)), 256, 0, stream>>>(x, xb, n8);

        dim3 dq_grid((unsigned)(((K / 8) / 32) * (N / 64)));
        dequant_w_kernel<<<dq_grid, 256, 0, stream>>>(qw, scales, zeros, Wt, N, K);

        dim3 grid((M / BM) * (N / BN));
        qgemm8_kernel<<<grid, 512, 0, stream>>>(xb, Wt, bias, out, M, N, K);
    } else {
        dim3 grid((M / FT_M) * (N / FT_N));
        qgemm_fused_kernel<<<grid, 256, 0, stream>>>(x, qw, scales, zeros, bias, out, M, N, K);
    }
}

// Round 14
// 293.548 us; speedup vs baseline: 1.1437x; 1.0539x over previous
//
#include <hip/hip_runtime.h>
#include <hip/hip_bf16.h>
#include <stdint.h>

// OldQuantLinear: y = x @ (scales.T * unpack4(qweight) - zeros.T) + bias
// R14: faithful m201-style 8-phase GEMM. 256x256 tile, BK=64, dbuf=2
// (128 KiB LDS), 8 waves (2M x 4N), MFMA 16x16x32, wave tile 128x64
// (8 m-frags x 4 n-frags). Per K-tile: 4 phases = (kk-half, nf-pair):
//   ph0: vmcnt(4); barrier; read A kk0 (8 b128) + B nf01 kk0 (2); stage
//        A0(t+1); setprio1; 16 MFMA; setprio0
//   ph1: read B nf23 kk0 (2, A reused); stage B0(t+1); 16 MFMA
//   ph2: vmcnt(pre?4:0); barrier; read A kk1 + B nf01 kk1; stage A1(t+1); 16 MFMA
//   ph3: read B nf23 kk1; stage B1(t+1); 16 MFMA
// Staging: half-tile = 256 rows x 32 k (16KB, 2 gload_lds/thread). vmcnt
// ledger: outstanding 8 at ph0/ph2 entry; vmcnt(4) retires exactly the two
// half-tiles needed; never drains to 0 mid-loop. Overwrite hazards separated
// by >=2 barriers (ledger in comments above each stage).

#define BM 256
#define BN 256
#define BK 64

using f32x4   = __attribute__((ext_vector_type(4))) float;
using bf16x8  = __attribute__((ext_vector_type(8))) __bf16;

typedef const uint32_t __attribute__((address_space(1)))* gas_ptr;
typedef uint32_t __attribute__((address_space(3)))* las_ptr;

__device__ __forceinline__ void gl16(const __bf16* g, __bf16* l) {
    __builtin_amdgcn_global_load_lds((gas_ptr)g, (las_ptr)l, 16, 0, 0);
}

// ---------------- pre-pass 1: x f32 -> bf16 ----------------
__global__ __launch_bounds__(256) void cvt_x_kernel(
    const float* __restrict__ x, __bf16* __restrict__ xb, size_t n8)
{
    size_t i = (size_t)blockIdx.x * 256 + threadIdx.x;
    if (i >= n8) return;
    const f32x4* p = (const f32x4*)(x + i * 8);
    f32x4 a = p[0], b = p[1];
    bf16x8 v;
    v[0] = (__bf16)a[0]; v[1] = (__bf16)a[1]; v[2] = (__bf16)a[2]; v[3] = (__bf16)a[3];
    v[4] = (__bf16)b[0]; v[5] = (__bf16)b[1]; v[6] = (__bf16)b[2]; v[7] = (__bf16)b[3];
    *(bf16x8*)(xb + i * 8) = v;
}

// ---------------- pre-pass 2: qweight -> Wt [N][K] bf16 ----------------
__global__ __launch_bounds__(256) void dequant_w_kernel(
    const int* __restrict__ qw, const float* __restrict__ scales,
    const float* __restrict__ zeros, __bf16* __restrict__ Wt, int N, int K)
{
    __shared__ __align__(16) __bf16 T[64 * 32 * 8];
    const int tid = threadIdx.x;
    const int nTilesN = N >> 6;
    const int kg0 = (blockIdx.x / nTilesN) << 5;
    const int n0  = (blockIdx.x % nTilesN) << 6;

    #pragma unroll
    for (int it = 0; it < 8; ++it) {
        int idx  = it * 256 + tid;
        int kg_l = idx >> 6, n_l = idx & 63;
        int n = n0 + n_l;
        float s = scales[n], nz = -zeros[n];
        uint32_t w  = (uint32_t)qw[(size_t)(kg0 + kg_l) * N + n];
        uint32_t lo = w & 0x0F0F0F0Fu;
        uint32_t hi = (w >> 4) & 0x0F0F0F0Fu;
        bf16x8 v;
        v[0] = (__bf16)fmaf(s, (float)(lo & 0xFFu),         nz);
        v[1] = (__bf16)fmaf(s, (float)(hi & 0xFFu),         nz);
        v[2] = (__bf16)fmaf(s, (float)((lo >> 8)  & 0xFFu), nz);
        v[3] = (__bf16)fmaf(s, (float)((hi >> 8)  & 0xFFu), nz);
        v[4] = (__bf16)fmaf(s, (float)((lo >> 16) & 0xFFu), nz);
        v[5] = (__bf16)fmaf(s, (float)((hi >> 16) & 0xFFu), nz);
        v[6] = (__bf16)fmaf(s, (float)(lo >> 24),           nz);
        v[7] = (__bf16)fmaf(s, (float)(hi >> 24),           nz);
        int slot = kg_l ^ (n_l & 7);
        *(bf16x8*)&T[(size_t)(n_l * 32 + slot) * 8] = v;
    }
    __syncthreads();
    #pragma unroll
    for (int it = 0; it < 8; ++it) {
        int idx  = it * 256 + tid;
        int n_l  = idx >> 5, kg_l = idx & 31;
        bf16x8 v = *(const bf16x8*)&T[(size_t)(n_l * 32 + (kg_l ^ (n_l & 7))) * 8];
        *(bf16x8*)&Wt[(size_t)(n0 + n_l) * K + (size_t)(kg0 + kg_l) * 8] = v;
    }
}

// ---------------- main GEMM: 8-phase, 16x16x32, BK=64, dbuf=2 ----------------
__global__ __launch_bounds__(512) void qgemm8_kernel(
    const __bf16* __restrict__ A, const __bf16* __restrict__ Bt,
    const float* __restrict__ bias, float* __restrict__ out,
    int M, int N, int K)
{
    // layout: [buf(2)][kh(2)][row(256)][k(32)] bf16, half = 8192 elems (16 KiB)
    __shared__ __align__(16) __bf16 Alds[2 * 2 * 256 * 32];  // 64 KiB
    __shared__ __align__(16) __bf16 Blds[2 * 2 * 256 * 32];  // 64 KiB

    const int tid = threadIdx.x;
    const int l   = tid & 63;
    const int w   = tid >> 6;
    const int wm  = w >> 2;        // 0..1 (M half, 128 rows)
    const int wn  = w & 3;         // 0..3 (N quarter, 64 cols)
    const int lr  = l & 15;        // fragment row
    const int lg  = l >> 4;        // 0..3 (k-group within 32-k half)

    // T1: bijective XCD swizzle (nwg % 8 == 0 for our shapes)
    int bid = (int)blockIdx.x;
    const int nwg = (int)gridDim.x;
    if ((nwg & 7) == 0) bid = (bid & 7) * (nwg >> 3) + (bid >> 3);

    const int nTilesN = N / BN;
    const int brow = (bid / nTilesN) * BM;
    const int bcol = (bid % nTilesN) * BN;

    // staging: half-tile = 256 rows x 32 k. Wave w instr j: granule
    // gi = (w*2+j)*64 + l -> row = (w*2+j)*16 + (l>>2), slot_pos = l&3.
    // content k-granule must be kb = sp ^ ((row>>1)&3) = (l&3) ^ ((l>>3)&3).
    const int skb  = (l & 3) ^ ((l >> 3) & 3);
    const int srow = w * 32 + (l >> 2);
    const __bf16* aSrc = A  + (size_t)(brow + srow) * K + skb * 8;
    const __bf16* bSrc = Bt + (size_t)(bcol + srow) * K + skb * 8;
    __bf16* aDst = &Alds[(size_t)w * 2 * 512];   // + buf/kh half base; HW adds lane*16B
    __bf16* bDst = &Blds[(size_t)w * 2 * 512];

    #define STAGE_A(tt, kh) { const size_t ko = (size_t)(tt) * BK + (kh) * 32;  \
        __bf16* d = aDst + ((((tt) & 1) * 2 + (kh)) * 8192);                    \
        gl16(aSrc + ko, d); gl16(aSrc + 16 * (size_t)K + ko, d + 512); }
    #define STAGE_B(tt, kh) { const size_t ko = (size_t)(tt) * BK + (kh) * 32;  \
        __bf16* d = bDst + ((((tt) & 1) * 2 + (kh)) * 8192);                    \
        gl16(bSrc + ko, d); gl16(bSrc + 16 * (size_t)K + ko, d + 512); }

    f32x4 acc[8][4];
    #pragma unroll
    for (int i = 0; i < 8; ++i)
        #pragma unroll
        for (int j = 0; j < 4; ++j)
            acc[i][j] = (f32x4){0.f, 0.f, 0.f, 0.f};

    const int NT = K / BK;

    // fragment reads: row = base + lr (+frag*16), slot = lg ^ ((row>>1)&3);
    // bases are multiples of 16 -> (row>>1)&3 == (lr>>1)&3 (frag-invariant).
    const int rsp = lg ^ ((lr >> 1) & 3);
    const int aoff = (wm * 128 + lr) * 32 + rsp * 8;   // + kh*8192 + buf*16384 + mf*512
    const int boff = (wn * 64  + lr) * 32 + rsp * 8;   // + kh*8192 + buf*16384 + nf*512

    // prologue: stage tile 0's four half-tiles (queue: A0,B0,A1,B1 = 8 loads)
    STAGE_A(0, 0); STAGE_B(0, 0);
    STAGE_A(0, 1); STAGE_B(0, 1);

    for (int t = 0; t < NT; ++t) {
        const int bb  = (t & 1) * 16384;
        const bool pre = (t + 1 < NT);
        bf16x8 af[8], bf0, bf1;

        // ---- ph0 (kk=0, nf 0-1) ----
        // outstanding = 8 [A0(t),B0(t),A1(t),B1(t)]; retire A0,B0
        asm volatile("s_waitcnt vmcnt(4)" ::: "memory");
        __builtin_amdgcn_sched_barrier(0);
        __builtin_amdgcn_s_barrier();
        __builtin_amdgcn_sched_barrier(0);
        #pragma unroll
        for (int mf = 0; mf < 8; ++mf)
            af[mf] = *(const bf16x8*)&Alds[bb + aoff + mf * 512];
        bf0 = *(const bf16x8*)&Blds[bb + boff];
        bf1 = *(const bf16x8*)&Blds[bb + boff + 512];
        // stage A0(t+1): overwrites A0(t-1), last read (t-1).ph1, two barriers ago
        if (pre) STAGE_A(t + 1, 0);
        __builtin_amdgcn_s_setprio(1);
        #pragma unroll
        for (int mf = 0; mf < 8; ++mf) {
            acc[mf][0] = __builtin_amdgcn_mfma_f32_16x16x32_bf16(af[mf], bf0, acc[mf][0], 0, 0, 0);
            acc[mf][1] = __builtin_amdgcn_mfma_f32_16x16x32_bf16(af[mf], bf1, acc[mf][1], 0, 0, 0);
        }
        __builtin_amdgcn_s_setprio(0);

        // ---- ph1 (kk=0, nf 2-3; A reused) ----
        bf0 = *(const bf16x8*)&Blds[bb + boff + 2 * 512];
        bf1 = *(const bf16x8*)&Blds[bb + boff + 3 * 512];
        if (pre) STAGE_B(t + 1, 0);
        __builtin_amdgcn_s_setprio(1);
        #pragma unroll
        for (int mf = 0; mf < 8; ++mf) {
            acc[mf][2] = __builtin_amdgcn_mfma_f32_16x16x32_bf16(af[mf], bf0, acc[mf][2], 0, 0, 0);
            acc[mf][3] = __builtin_amdgcn_mfma_f32_16x16x32_bf16(af[mf], bf1, acc[mf][3], 0, 0, 0);
        }
        __builtin_amdgcn_s_setprio(0);

        // ---- ph2 (kk=1, nf 0-1) ----
        // outstanding = [A1(t),B1(t),A0(t+1),B0(t+1)]; retire A1(t),B1(t)
        if (pre) { asm volatile("s_waitcnt vmcnt(4)" ::: "memory"); }
        else     { asm volatile("s_waitcnt vmcnt(0)" ::: "memory"); }
        __builtin_amdgcn_sched_barrier(0);
        __builtin_amdgcn_s_barrier();
        __builtin_amdgcn_sched_barrier(0);
        #pragma unroll
        for (int mf = 0; mf < 8; ++mf)
            af[mf] = *(const bf16x8*)&Alds[bb + 8192 + aoff + mf * 512];
        bf0 = *(const bf16x8*)&Blds[bb + 8192 + boff];
        bf1 = *(const bf16x8*)&Blds[bb + 8192 + boff + 512];
        if (pre) STAGE_A(t + 1, 1);
        __builtin_amdgcn_s_setprio(1);
        #pragma unroll
        for (int mf = 0; mf < 8; ++mf) {
            acc[mf][0] = __builtin_amdgcn_mfma_f32_16x16x32_bf16(af[mf], bf0, acc[mf][0], 0, 0, 0);
            acc[mf][1] = __builtin_amdgcn_mfma_f32_16x16x32_bf16(af[mf], bf1, acc[mf][1], 0, 0, 0);
        }
        __builtin_amdgcn_s_setprio(0);

        // ---- ph3 (kk=1, nf 2-3) ----
        bf0 = *(const bf16x8*)&Blds[bb + 8192 + boff + 2 * 512];
        bf1 = *(const bf16x8*)&Blds[bb + 8192 + boff + 3 * 512];
        if (pre) STAGE_B(t + 1, 1);
        __builtin_amdgcn_s_setprio(1);
        #pragma unroll
        for (int mf = 0; mf < 8; ++mf) {
            acc[mf][2] = __builtin_amdgcn_mfma_f32_16x16x32_bf16(af[mf], bf0, acc[mf][2], 0, 0, 0);
            acc[mf][3] = __builtin_amdgcn_mfma_f32_16x16x32_bf16(af[mf], bf1, acc[mf][3], 0, 0, 0);
        }
        __builtin_amdgcn_s_setprio(0);
    }

    // ---- epilogue: 16x16 C/D layout: col = lane&15, row = (lane>>4)*4 + i ----
    #pragma unroll
    for (int nf = 0; nf < 4; ++nf) {
        int col = bcol + wn * 64 + nf * 16 + lr;
        float bv = bias[col];
        #pragma unroll
        for (int mf = 0; mf < 8; ++mf) {
            int row = brow + wm * 128 + mf * 16 + lg * 4;
            #pragma unroll
            for (int i = 0; i < 4; ++i)
                out[(size_t)(row + i) * N + col] = acc[mf][nf][i] + bv;
        }
    }
    #undef STAGE_A
    #undef STAGE_B
}

// ---------------- fallback: fused kernel (R2) ----------------
#define FT_M 128
#define FT_N 128
#define FT_K 64
__global__ __launch_bounds__(256) void qgemm_fused_kernel(
    const float* __restrict__ x, const int* __restrict__ qw,
    const float* __restrict__ scales, const float* __restrict__ zeros,
    const float* __restrict__ bias, float* __restrict__ out,
    int M, int N, int K)
{
    __shared__ __align__(16) __bf16 Alds[FT_M * FT_K];
    __shared__ __align__(16) __bf16 Blds[FT_N * FT_K];

    const int tid  = threadIdx.x;
    const int lane = tid & 63;
    const int wave = tid >> 6;
    const int wm = wave >> 1, wn = wave & 1;
    const int lrow = lane & 15, lkb = lane >> 4;

    const int nTilesN = N / FT_N;
    const int brow = (blockIdx.x / nTilesN) * FT_M;
    const int bcol = (blockIdx.x % nTilesN) * FT_N;

    const int bc  = tid & 127;
    const int qr0 = tid >> 7;
    const float s  = scales[bcol + bc];
    const float nz = -zeros[bcol + bc];

    f32x4 acc[4][4];
    #pragma unroll
    for (int i = 0; i < 4; ++i)
        #pragma unroll
        for (int j = 0; j < 4; ++j)
            acc[i][j] = (f32x4){0.f, 0.f, 0.f, 0.f};

    for (int kt = 0; kt < K; kt += FT_K) {
        #pragma unroll
        for (int i = 0; i < 4; ++i) {
            int g  = tid + i * 256;
            int r  = g >> 3;
            int kbg = g & 7;
            const float* p = x + (size_t)(brow + r) * K + kt + kbg * 8;
            f32x4 f0 = *(const f32x4*)p;
            f32x4 f1 = *(const f32x4*)(p + 4);
            bf16x8 v;
            v[0] = (__bf16)f0[0]; v[1] = (__bf16)f0[1];
            v[2] = (__bf16)f0[2]; v[3] = (__bf16)f0[3];
            v[4] = (__bf16)f1[0]; v[5] = (__bf16)f1[1];
            v[6] = (__bf16)f1[2]; v[7] = (__bf16)f1[3];
            int slot = kbg ^ (r & 7);
            *(bf16x8*)&Alds[r * FT_K + slot * 8] = v;
        }
        #pragma unroll
        for (int i = 0; i < 4; ++i) {
            int qr = qr0 + i * 2;
            uint32_t wv = (uint32_t)qw[(size_t)(kt / 8 + qr) * N + bcol + bc];
            uint32_t lo = wv & 0x0F0F0F0Fu;
            uint32_t hi = (wv >> 4) & 0x0F0F0F0Fu;
            bf16x8 v;
            v[0] = (__bf16)fmaf(s, (float)(lo & 0xFFu),         nz);
            v[1] = (__bf16)fmaf(s, (float)(hi & 0xFFu),         nz);
            v[2] = (__bf16)fmaf(s, (float)((lo >> 8)  & 0xFFu), nz);
            v[3] = (__bf16)fmaf(s, (float)((hi >> 8)  & 0xFFu), nz);
            v[4] = (__bf16)fmaf(s, (float)((lo >> 16) & 0xFFu), nz);
            v[5] = (__bf16)fmaf(s, (float)((hi >> 16) & 0xFFu), nz);
            v[6] = (__bf16)fmaf(s, (float)(lo >> 24),           nz);
            v[7] = (__bf16)fmaf(s, (float)(hi >> 24),           nz);
            int slot = qr ^ (bc & 7);
            *(bf16x8*)&Blds[bc * FT_K + slot * 8] = v;
        }
        __syncthreads();

        #pragma unroll
        for (int ks = 0; ks < 2; ++ks) {
            const int slot = (ks * 4 + lkb) ^ (lrow & 7);
            const int abase = (wm * 64 + lrow) * FT_K + slot * 8;
            const int bbase = (wn * 64 + lrow) * FT_K + slot * 8;
            bf16x8 af[4], bfr[4];
            #pragma unroll
            for (int mf = 0; mf < 4; ++mf)
                af[mf] = *(const bf16x8*)&Alds[abase + mf * 16 * FT_K];
            #pragma unroll
            for (int nf = 0; nf < 4; ++nf)
                bfr[nf] = *(const bf16x8*)&Blds[bbase + nf * 16 * FT_K];
            #pragma unroll
            for (int mf = 0; mf < 4; ++mf)
                #pragma unroll
                for (int nf = 0; nf < 4; ++nf)
                    acc[mf][nf] = __builtin_amdgcn_mfma_f32_16x16x32_bf16(
                        af[mf], bfr[nf], acc[mf][nf], 0, 0, 0);
        }
        __syncthreads();
    }

    #pragma unroll
    for (int nf = 0; nf < 4; ++nf) {
        int col = bcol + wn * 64 + nf * 16 + lrow;
        float bv = bias[col];
        #pragma unroll
        for (int mf = 0; mf < 4; ++mf) {
            int row = brow + wm * 64 + mf * 16 + lkb * 4;
            #pragma unroll
            for (int i = 0; i < 4; ++i)
                out[(size_t)(row + i) * N + col] = acc[mf][nf][i] + bv;
        }
    }
}

extern "C" void kernel_launch(void* const* d_in, const int* in_sizes, int n_in,
                              void* d_out, int out_size, void* d_ws, size_t ws_size,
                              hipStream_t stream) {
    const float* x      = (const float*)d_in[0];
    const int*   qw     = (const int*)d_in[1];
    const float* scales = (const float*)d_in[2];
    const float* zeros  = (const float*)d_in[3];
    const float* bias   = (const float*)d_in[4];
    float* out = (float*)d_out;

    const int N = in_sizes[4];                              // OUT
    const int K = (int)(((long long)in_sizes[1] * 8) / N);  // IN
    const int M = in_sizes[0] / K;

    const size_t xb_elems = (size_t)M * K;
    const size_t wt_elems = (size_t)N * K;
    const size_t need = (xb_elems + wt_elems) * sizeof(__bf16);

    const bool shapes_ok = (M % BM == 0) && (N % BN == 0) && (K % 256 == 0) &&
                           (K / BK >= 2);

    if (ws_size >= need && shapes_ok) {
        __bf16* xb = (__bf16*)d_ws;
        __bf16* Wt = xb + xb_elems;

        size_t n8 = xb_elems / 8;
        cvt_x_kernel<<<dim3((unsigned)((n8 + 255) / 256)), 256, 0, stream>>>(x, xb, n8);

        dim3 dq_grid((unsigned)(((K / 8) / 32) * (N / 64)));
        dequant_w_kernel<<<dq_grid, 256, 0, stream>>>(qw, scales, zeros, Wt, N, K);

        dim3 grid((M / BM) * (N / BN));
        qgemm8_kernel<<<grid, 512, 0, stream>>>(xb, Wt, bias, out, M, N, K);
    } else {
        dim3 grid((M / FT_M) * (N / FT_N));
        qgemm_fused_kernel<<<grid, 256, 0, stream>>>(x, qw, scales, zeros, bias, out, M, N, K);
    }
}